// Round 1
// baseline (6886.796 us; speedup 1.0000x reference)
//
#include <hip/hip_runtime.h>

#define BB 8
#define CC 512
#define NN 4096
#define GG 32
#define OQKV 1536
#define EPSV 1e-5f
#define SCALE 0.044194173824159216f  // 1/sqrt(512)

typedef unsigned short u16;
typedef unsigned int u32;

__device__ __forceinline__ u16 f2bf(float f) {
  u32 u = __float_as_uint(f);
  u32 r = (u + 0x7FFFu + ((u >> 16) & 1u)) >> 16;  // RNE
  return (u16)r;
}

// ---------------- GroupNorm statistics: one block per (b, group) ----------------
__global__ __launch_bounds__(256) void gn_stats_kernel(const float* __restrict__ x,
                                                       float* __restrict__ stats) {
  const int bg = blockIdx.x;  // b*32 + g ; group covers 16 channels * 4096 = 65536 elems
  const float4* xp = (const float4*)(x + (size_t)bg * 16 * NN);
  const int n4 = 16 * NN / 4;  // 16384
  float s = 0.f, ss = 0.f;
  for (int i = threadIdx.x; i < n4; i += 256) {
    float4 v = xp[i];
    s += v.x + v.y + v.z + v.w;
    ss += v.x * v.x + v.y * v.y + v.z * v.z + v.w * v.w;
  }
  for (int off = 32; off > 0; off >>= 1) {
    s += __shfl_down(s, off, 64);
    ss += __shfl_down(ss, off, 64);
  }
  __shared__ float rs[4], rss[4];
  const int wid = threadIdx.x >> 6, lane = threadIdx.x & 63;
  if (lane == 0) { rs[wid] = s; rss[wid] = ss; }
  __syncthreads();
  if (threadIdx.x == 0) {
    float S = rs[0] + rs[1] + rs[2] + rs[3];
    float SS = rss[0] + rss[1] + rss[2] + rss[3];
    const float invn = 1.0f / (16.0f * NN);
    float mean = S * invn;
    float var = SS * invn - mean * mean;
    stats[bg * 2] = mean;
    stats[bg * 2 + 1] = rsqrtf(var + EPSV);
  }
}

// ------------- QKV GEMM with fused GroupNorm, bf16 output -------------
// per batch: qkv[o][n] = sum_c W[o][c]*hhat[c][n] + b[o],  o<1536, n<4096
__global__ __launch_bounds__(256) void qkv_gemm_kernel(
    const float* __restrict__ x, const float* __restrict__ gamma,
    const float* __restrict__ beta, const float* __restrict__ wqkv,
    const float* __restrict__ bqkv, const float* __restrict__ stats,
    u16* __restrict__ qkv) {
  __shared__ __align__(16) float Wt[16][68];
  __shared__ __align__(16) float Ht[16][68];
  const int b = blockIdx.z;
  const int o0 = blockIdx.y * 64;
  const int n0 = blockIdx.x * 64;
  const int t = threadIdx.x;
  const int to = (t >> 4) * 4;
  const int tn = (t & 15) * 4;
  const int wo = t >> 2;
  const int wk = (t & 3) * 4;
  const int xc = t >> 4;
  const int xn = (t & 15) * 4;
  const float* xb = x + (size_t)b * CC * NN;
  float acc[4][4] = {{0.f}};
  for (int kk = 0; kk < CC; kk += 16) {
    float4 wv = *(const float4*)(wqkv + (size_t)(o0 + wo) * CC + kk + wk);
    const int c = kk + xc;
    const int g = c >> 4;
    const float mean = stats[(b * GG + g) * 2];
    const float rstd = stats[(b * GG + g) * 2 + 1];
    const float aa = rstd * gamma[c];
    const float dd = beta[c] - mean * aa;
    float4 xv = *(const float4*)(xb + (size_t)c * NN + n0 + xn);
    __syncthreads();
    Wt[wk + 0][wo] = wv.x;
    Wt[wk + 1][wo] = wv.y;
    Wt[wk + 2][wo] = wv.z;
    Wt[wk + 3][wo] = wv.w;
    float4 hv;
    hv.x = fmaf(aa, xv.x, dd);
    hv.y = fmaf(aa, xv.y, dd);
    hv.z = fmaf(aa, xv.z, dd);
    hv.w = fmaf(aa, xv.w, dd);
    *(float4*)&Ht[xc][xn] = hv;
    __syncthreads();
#pragma unroll
    for (int k = 0; k < 16; ++k) {
      float4 w4 = *(const float4*)&Wt[k][to];
      float4 h4 = *(const float4*)&Ht[k][tn];
      acc[0][0] = fmaf(w4.x, h4.x, acc[0][0]);
      acc[0][1] = fmaf(w4.x, h4.y, acc[0][1]);
      acc[0][2] = fmaf(w4.x, h4.z, acc[0][2]);
      acc[0][3] = fmaf(w4.x, h4.w, acc[0][3]);
      acc[1][0] = fmaf(w4.y, h4.x, acc[1][0]);
      acc[1][1] = fmaf(w4.y, h4.y, acc[1][1]);
      acc[1][2] = fmaf(w4.y, h4.z, acc[1][2]);
      acc[1][3] = fmaf(w4.y, h4.w, acc[1][3]);
      acc[2][0] = fmaf(w4.z, h4.x, acc[2][0]);
      acc[2][1] = fmaf(w4.z, h4.y, acc[2][1]);
      acc[2][2] = fmaf(w4.z, h4.z, acc[2][2]);
      acc[2][3] = fmaf(w4.z, h4.w, acc[2][3]);
      acc[3][0] = fmaf(w4.w, h4.x, acc[3][0]);
      acc[3][1] = fmaf(w4.w, h4.y, acc[3][1]);
      acc[3][2] = fmaf(w4.w, h4.z, acc[3][2]);
      acc[3][3] = fmaf(w4.w, h4.w, acc[3][3]);
    }
  }
  u16* qb = qkv + (size_t)b * OQKV * NN;
#pragma unroll
  for (int i = 0; i < 4; ++i) {
    const int o = o0 + to + i;
    const float bias = bqkv[o];
    const size_t base = (size_t)o * NN + n0 + tn;
    qb[base + 0] = f2bf(acc[i][0] + bias);
    qb[base + 1] = f2bf(acc[i][1] + bias);
    qb[base + 2] = f2bf(acc[i][2] + bias);
    qb[base + 3] = f2bf(acc[i][3] + bias);
  }
}

// ------------- Flash attention (vector fp32 math, bf16 operands) -------------
// one block = 32 query rows of one batch; loop over all 4096 keys in 32-wide tiles
__global__ __launch_bounds__(256) void attn_kernel(const u16* __restrict__ qkv,
                                                   float* __restrict__ obuf) {
  __shared__ __align__(16) u16 qs[CC][32];     // q[c][ii]            32 KB
  __shared__ __align__(16) u16 kvbuf[16448];   // K tile then V^T tile 32.9 KB
  __shared__ float ps[32][33];                 // scores/probs
  __shared__ float m_s[32], l_s[32], alpha_s[32];

  const int b = blockIdx.y;
  const int i0 = blockIdx.x * 32;
  const int t = threadIdx.x;
  const u16* qb = qkv + (size_t)b * OQKV * NN;
  const u16* kb = qb + (size_t)CC * NN;
  const u16* vb = kb + (size_t)CC * NN;

  const int cr = t >> 4;          // 0..15 (channel sub-row for loads)
  const int col = (t & 15) * 2;   // 0..30 (pair of columns for loads)
#pragma unroll 4
  for (int r = 0; r < 32; ++r) {
    const int c = r * 16 + cr;
    *(ushort2*)&qs[c][col] = *(const ushort2*)(qb + (size_t)c * NN + i0 + col);
  }
  if (t < 32) { m_s[t] = -1e30f; l_s[t] = 0.f; }

  float acc[16][4];
#pragma unroll
  for (int i = 0; i < 16; ++i)
#pragma unroll
    for (int r = 0; r < 4; ++r) acc[i][r] = 0.f;

  const int sii = (t >> 4) * 2;   // score-phase: 2 rows
  const int sjj = (t & 15) * 2;   // score-phase: 2 cols
  const int cg = t >> 3;          // PV-phase: 16 channels starting cg*16
  const int iig4 = (t & 7) * 4;   // PV-phase: 4 query rows

  for (int j0 = 0; j0 < NN; j0 += 32) {
    __syncthreads();  // prev PV done before K overwrites kvbuf
#pragma unroll 4
    for (int r = 0; r < 32; ++r) {
      const int c = r * 16 + cr;
      *(ushort2*)&kvbuf[c * 32 + col] = *(const ushort2*)(kb + (size_t)c * NN + j0 + col);
    }
    __syncthreads();
    float s00 = 0.f, s01 = 0.f, s10 = 0.f, s11 = 0.f;
#pragma unroll 8
    for (int c = 0; c < CC; ++c) {
      const u32 qp = *(const u32*)&qs[c][sii];
      const u32 kp = *(const u32*)&kvbuf[c * 32 + sjj];
      const float q0 = __uint_as_float(qp << 16);
      const float q1 = __uint_as_float(qp & 0xffff0000u);
      const float k0 = __uint_as_float(kp << 16);
      const float k1 = __uint_as_float(kp & 0xffff0000u);
      s00 = fmaf(q0, k0, s00);
      s01 = fmaf(q0, k1, s01);
      s10 = fmaf(q1, k0, s10);
      s11 = fmaf(q1, k1, s11);
    }
    ps[sii][sjj] = s00 * SCALE;
    ps[sii][sjj + 1] = s01 * SCALE;
    ps[sii + 1][sjj] = s10 * SCALE;
    ps[sii + 1][sjj + 1] = s11 * SCALE;
    __syncthreads();  // S reads of K done; ps complete
    // load V^T into kvbuf (overwrites K) while 32 threads run softmax
#pragma unroll 4
    for (int r = 0; r < 32; ++r) {
      const int c = r * 16 + cr;
      const ushort2 vv = *(const ushort2*)(vb + (size_t)c * NN + j0 + col);
      kvbuf[col * 514 + c] = vv.x;
      kvbuf[(col + 1) * 514 + c] = vv.y;
    }
    if (t < 32) {
      const float mold = m_s[t];
      float mmax = mold;
#pragma unroll
      for (int j = 0; j < 32; ++j) mmax = fmaxf(mmax, ps[t][j]);
      const float alpha = __expf(mold - mmax);
      float sum = 0.f;
#pragma unroll
      for (int j = 0; j < 32; ++j) {
        const float p = __expf(ps[t][j] - mmax);
        ps[t][j] = p;
        sum += p;
      }
      m_s[t] = mmax;
      l_s[t] = l_s[t] * alpha + sum;
      alpha_s[t] = alpha;
    }
    __syncthreads();
    const float a0 = alpha_s[iig4 + 0];
    const float a1 = alpha_s[iig4 + 1];
    const float a2 = alpha_s[iig4 + 2];
    const float a3 = alpha_s[iig4 + 3];
#pragma unroll
    for (int i = 0; i < 16; ++i) {
      acc[i][0] *= a0; acc[i][1] *= a1; acc[i][2] *= a2; acc[i][3] *= a3;
    }
    for (int jj = 0; jj < 32; ++jj) {
      const float p0 = ps[iig4 + 0][jj];
      const float p1 = ps[iig4 + 1][jj];
      const float p2 = ps[iig4 + 2][jj];
      const float p3 = ps[iig4 + 3][jj];
      const u16* vrow = &kvbuf[jj * 514 + cg * 16];
#pragma unroll
      for (int i = 0; i < 16; i += 2) {
        const u32 vp = *(const u32*)&vrow[i];
        const float v0 = __uint_as_float(vp << 16);
        const float v1 = __uint_as_float(vp & 0xffff0000u);
        acc[i][0] = fmaf(v0, p0, acc[i][0]);
        acc[i][1] = fmaf(v0, p1, acc[i][1]);
        acc[i][2] = fmaf(v0, p2, acc[i][2]);
        acc[i][3] = fmaf(v0, p3, acc[i][3]);
        acc[i + 1][0] = fmaf(v1, p0, acc[i + 1][0]);
        acc[i + 1][1] = fmaf(v1, p1, acc[i + 1][1]);
        acc[i + 1][2] = fmaf(v1, p2, acc[i + 1][2]);
        acc[i + 1][3] = fmaf(v1, p3, acc[i + 1][3]);
      }
    }
  }
  const float inv0 = 1.f / l_s[iig4 + 0];
  const float inv1 = 1.f / l_s[iig4 + 1];
  const float inv2 = 1.f / l_s[iig4 + 2];
  const float inv3 = 1.f / l_s[iig4 + 3];
  float* ob2 = obuf + (size_t)b * CC * NN;
#pragma unroll
  for (int i = 0; i < 16; ++i) {
    const size_t base = (size_t)(cg * 16 + i) * NN + i0 + iig4;
    ob2[base + 0] = acc[i][0] * inv0;
    ob2[base + 1] = acc[i][1] * inv1;
    ob2[base + 2] = acc[i][2] * inv2;
    ob2[base + 3] = acc[i][3] * inv3;
  }
}

// ------------- output projection + bias + residual -------------
__global__ __launch_bounds__(256) void proj_kernel(
    const float* __restrict__ obuf, const float* __restrict__ wout,
    const float* __restrict__ bout, const float* __restrict__ x,
    float* __restrict__ out) {
  __shared__ __align__(16) float Wt[16][68];
  __shared__ __align__(16) float Ht[16][68];
  const int b = blockIdx.z;
  const int o0 = blockIdx.y * 64;
  const int n0 = blockIdx.x * 64;
  const int t = threadIdx.x;
  const int to = (t >> 4) * 4;
  const int tn = (t & 15) * 4;
  const int wo = t >> 2;
  const int wk = (t & 3) * 4;
  const int xc = t >> 4;
  const int xn = (t & 15) * 4;
  const float* ob = obuf + (size_t)b * CC * NN;
  float acc[4][4] = {{0.f}};
  for (int kk = 0; kk < CC; kk += 16) {
    float4 wv = *(const float4*)(wout + (size_t)(o0 + wo) * CC + kk + wk);
    float4 hv = *(const float4*)(ob + (size_t)(kk + xc) * NN + n0 + xn);
    __syncthreads();
    Wt[wk + 0][wo] = wv.x;
    Wt[wk + 1][wo] = wv.y;
    Wt[wk + 2][wo] = wv.z;
    Wt[wk + 3][wo] = wv.w;
    *(float4*)&Ht[xc][xn] = hv;
    __syncthreads();
#pragma unroll
    for (int k = 0; k < 16; ++k) {
      float4 w4 = *(const float4*)&Wt[k][to];
      float4 h4 = *(const float4*)&Ht[k][tn];
      acc[0][0] = fmaf(w4.x, h4.x, acc[0][0]);
      acc[0][1] = fmaf(w4.x, h4.y, acc[0][1]);
      acc[0][2] = fmaf(w4.x, h4.z, acc[0][2]);
      acc[0][3] = fmaf(w4.x, h4.w, acc[0][3]);
      acc[1][0] = fmaf(w4.y, h4.x, acc[1][0]);
      acc[1][1] = fmaf(w4.y, h4.y, acc[1][1]);
      acc[1][2] = fmaf(w4.y, h4.z, acc[1][2]);
      acc[1][3] = fmaf(w4.y, h4.w, acc[1][3]);
      acc[2][0] = fmaf(w4.z, h4.x, acc[2][0]);
      acc[2][1] = fmaf(w4.z, h4.y, acc[2][1]);
      acc[2][2] = fmaf(w4.z, h4.z, acc[2][2]);
      acc[2][3] = fmaf(w4.z, h4.w, acc[2][3]);
      acc[3][0] = fmaf(w4.w, h4.x, acc[3][0]);
      acc[3][1] = fmaf(w4.w, h4.y, acc[3][1]);
      acc[3][2] = fmaf(w4.w, h4.z, acc[3][2]);
      acc[3][3] = fmaf(w4.w, h4.w, acc[3][3]);
    }
  }
#pragma unroll
  for (int i = 0; i < 4; ++i) {
    const int o = o0 + to + i;
    const float bias = bout[o];
    const size_t idx = ((size_t)b * CC + o) * NN + n0 + tn;
    float4 xv = *(const float4*)(x + idx);
    float4 r;
    r.x = acc[i][0] + bias + xv.x;
    r.y = acc[i][1] + bias + xv.y;
    r.z = acc[i][2] + bias + xv.z;
    r.w = acc[i][3] + bias + xv.w;
    *(float4*)(out + idx) = r;
  }
}

extern "C" void kernel_launch(void* const* d_in, const int* in_sizes, int n_in,
                              void* d_out, int out_size, void* d_ws, size_t ws_size,
                              hipStream_t stream) {
  const float* x = (const float*)d_in[0];
  const float* gamma = (const float*)d_in[1];
  const float* beta = (const float*)d_in[2];
  const float* wqkv = (const float*)d_in[3];
  const float* bqkv = (const float*)d_in[4];
  const float* wout = (const float*)d_in[5];
  const float* bout = (const float*)d_in[6];
  float* out = (float*)d_out;

  char* ws = (char*)d_ws;
  float* stats = (float*)ws;                                   // 2 KB
  u16* qkv = (u16*)(ws + 4096);                                // 100.66 MB bf16
  float* obuf = (float*)(ws + 4096 + (size_t)BB * OQKV * NN * 2);  // 67.1 MB fp32

  gn_stats_kernel<<<BB * GG, 256, 0, stream>>>(x, stats);
  qkv_gemm_kernel<<<dim3(NN / 64, OQKV / 64, BB), 256, 0, stream>>>(
      x, gamma, beta, wqkv, bqkv, stats, qkv);
  attn_kernel<<<dim3(NN / 32, BB), 256, 0, stream>>>(qkv, obuf);
  proj_kernel<<<dim3(NN / 64, CC / 64, BB), 256, 0, stream>>>(obuf, wout, bout, x, out);
}

// Round 2
// 2031.322 us; speedup vs baseline: 3.3903x; 3.3903x over previous
//
#include <hip/hip_runtime.h>

#define BB 8
#define CC 512
#define NN 4096
#define GG 32
#define OQKV 1536
#define EPSV 1e-5f
#define SCALE 0.044194173824159216f  // 1/sqrt(512)

// per-batch u16 offsets inside the qkv workspace region: [v | q | k]
#define BATCH_STRIDE 6291456u   // 1536*4096
#define V_OFF 0u
#define Q_OFF 2097152u          // 512*4096
#define K_OFF 4194304u

typedef unsigned short u16;
typedef unsigned int u32;
typedef __attribute__((ext_vector_type(8))) short bf16x8;
typedef __attribute__((ext_vector_type(4))) float f32x4;

__device__ __forceinline__ u16 f2bf(float f) {
  u32 u = __float_as_uint(f);
  u32 r = (u + 0x7FFFu + ((u >> 16) & 1u)) >> 16;  // RNE
  return (u16)r;
}

// ---------------- GroupNorm statistics: one block per (b, group) ----------------
__global__ __launch_bounds__(256) void gn_stats_kernel(const float* __restrict__ x,
                                                       float* __restrict__ stats) {
  const int bg = blockIdx.x;
  const float4* xp = (const float4*)(x + (size_t)bg * 16 * NN);
  const int n4 = 16 * NN / 4;
  float s = 0.f, ss = 0.f;
  for (int i = threadIdx.x; i < n4; i += 256) {
    float4 v = xp[i];
    s += v.x + v.y + v.z + v.w;
    ss += v.x * v.x + v.y * v.y + v.z * v.z + v.w * v.w;
  }
  for (int off = 32; off > 0; off >>= 1) {
    s += __shfl_down(s, off, 64);
    ss += __shfl_down(ss, off, 64);
  }
  __shared__ float rs[4], rss[4];
  const int wid = threadIdx.x >> 6, lane = threadIdx.x & 63;
  if (lane == 0) { rs[wid] = s; rss[wid] = ss; }
  __syncthreads();
  if (threadIdx.x == 0) {
    float S = rs[0] + rs[1] + rs[2] + rs[3];
    float SS = rss[0] + rss[1] + rss[2] + rss[3];
    const float invn = 1.0f / (16.0f * NN);
    float mean = S * invn;
    float var = SS * invn - mean * mean;
    stats[bg * 2] = mean;
    stats[bg * 2 + 1] = rsqrtf(var + EPSV);
  }
}

// ------------- QKV GEMM with fused GroupNorm, bf16 output into [v|q|k] regions -------------
__global__ __launch_bounds__(256) void qkv_gemm_kernel(
    const float* __restrict__ x, const float* __restrict__ gamma,
    const float* __restrict__ beta, const float* __restrict__ wqkv,
    const float* __restrict__ bqkv, const float* __restrict__ stats,
    u16* __restrict__ qkv) {
  __shared__ __align__(16) float Wt[16][68];
  __shared__ __align__(16) float Ht[16][68];
  const int b = blockIdx.z;
  const int o0 = blockIdx.y * 64;
  const int n0 = blockIdx.x * 64;
  const int t = threadIdx.x;
  const int to = (t >> 4) * 4;
  const int tn = (t & 15) * 4;
  const int wo = t >> 2;
  const int wk = (t & 3) * 4;
  const int xc = t >> 4;
  const int xn = (t & 15) * 4;
  const float* xb = x + (size_t)b * CC * NN;
  float acc[4][4] = {{0.f}};
  for (int kk = 0; kk < CC; kk += 16) {
    float4 wv = *(const float4*)(wqkv + (size_t)(o0 + wo) * CC + kk + wk);
    const int c = kk + xc;
    const int g = c >> 4;
    const float mean = stats[(b * GG + g) * 2];
    const float rstd = stats[(b * GG + g) * 2 + 1];
    const float aa = rstd * gamma[c];
    const float dd = beta[c] - mean * aa;
    float4 xv = *(const float4*)(xb + (size_t)c * NN + n0 + xn);
    __syncthreads();
    Wt[wk + 0][wo] = wv.x;
    Wt[wk + 1][wo] = wv.y;
    Wt[wk + 2][wo] = wv.z;
    Wt[wk + 3][wo] = wv.w;
    float4 hv;
    hv.x = fmaf(aa, xv.x, dd);
    hv.y = fmaf(aa, xv.y, dd);
    hv.z = fmaf(aa, xv.z, dd);
    hv.w = fmaf(aa, xv.w, dd);
    *(float4*)&Ht[xc][xn] = hv;
    __syncthreads();
#pragma unroll
    for (int k = 0; k < 16; ++k) {
      float4 w4 = *(const float4*)&Wt[k][to];
      float4 h4 = *(const float4*)&Ht[k][tn];
      acc[0][0] = fmaf(w4.x, h4.x, acc[0][0]);
      acc[0][1] = fmaf(w4.x, h4.y, acc[0][1]);
      acc[0][2] = fmaf(w4.x, h4.z, acc[0][2]);
      acc[0][3] = fmaf(w4.x, h4.w, acc[0][3]);
      acc[1][0] = fmaf(w4.y, h4.x, acc[1][0]);
      acc[1][1] = fmaf(w4.y, h4.y, acc[1][1]);
      acc[1][2] = fmaf(w4.y, h4.z, acc[1][2]);
      acc[1][3] = fmaf(w4.y, h4.w, acc[1][3]);
      acc[2][0] = fmaf(w4.z, h4.x, acc[2][0]);
      acc[2][1] = fmaf(w4.z, h4.y, acc[2][1]);
      acc[2][2] = fmaf(w4.z, h4.z, acc[2][2]);
      acc[2][3] = fmaf(w4.z, h4.w, acc[2][3]);
      acc[3][0] = fmaf(w4.w, h4.x, acc[3][0]);
      acc[3][1] = fmaf(w4.w, h4.y, acc[3][1]);
      acc[3][2] = fmaf(w4.w, h4.z, acc[3][2]);
      acc[3][3] = fmaf(w4.w, h4.w, acc[3][3]);
    }
  }
  // region select: o0 in [0,512)=q, [512,1024)=k, [1024,1536)=v (uniform per block)
  u16* qb = qkv + (size_t)b * BATCH_STRIDE;
  size_t roff;
  int lo0;
  if (o0 < 512) { roff = Q_OFF; lo0 = o0; }
  else if (o0 < 1024) { roff = K_OFF; lo0 = o0 - 512; }
  else { roff = V_OFF; lo0 = o0 - 1024; }
#pragma unroll
  for (int i = 0; i < 4; ++i) {
    const int o = o0 + to + i;
    const float bias = bqkv[o];
    const size_t base = roff + (size_t)(lo0 + to + i) * NN + n0 + tn;
    qb[base + 0] = f2bf(acc[i][0] + bias);
    qb[base + 1] = f2bf(acc[i][1] + bias);
    qb[base + 2] = f2bf(acc[i][2] + bias);
    qb[base + 3] = f2bf(acc[i][3] + bias);
  }
}

// ------------- 64x64 tile transpose q,k: [c][n] -> [n][c] bf16 -------------
__global__ __launch_bounds__(256) void transpose_qk_kernel(
    const u16* __restrict__ qkvbuf, u16* __restrict__ qT, u16* __restrict__ kT) {
  __shared__ __align__(16) u16 Ts[64 * 64];  // XOR-swizzled 16B units
  const int b = blockIdx.z >> 1;
  const int which = blockIdx.z & 1;
  const int c0 = blockIdx.y * 64;
  const int n0 = blockIdx.x * 64;
  const int t = threadIdx.x;
  const u16* src = qkvbuf + (size_t)b * BATCH_STRIDE + (which ? K_OFF : Q_OFF);
  u16* dst = (which ? kT : qT) + (size_t)b * (CC * NN);
#pragma unroll
  for (int it = 0; it < 2; ++it) {
    const int U = it * 256 + t;
    const int r = U >> 3, cu = U & 7;
    const int pu = cu ^ ((r >> 3) & 7);
    *(uint4*)((char*)Ts + r * 128 + pu * 16) =
        *(const uint4*)(src + (size_t)(c0 + r) * NN + n0 + cu * 8);
  }
  __syncthreads();
#pragma unroll
  for (int it = 0; it < 2; ++it) {
    const int U = it * 256 + t;
    const int n = U >> 3, cu2 = U & 7;
    bf16x8 v;
#pragma unroll
    for (int jj = 0; jj < 8; ++jj) {
      const int c = cu2 * 8 + jj;
      v[jj] = (short)Ts[c * 64 + (((n >> 3) ^ cu2) << 3) + (n & 7)];
    }
    *(bf16x8*)(dst + (size_t)(n0 + n) * CC + c0 + cu2 * 8) = v;
  }
}

// ------------- Flash attention on MFMA (bf16), BQ=64, TK=32, 512 threads -------------
__global__ __launch_bounds__(512, 2) void attn_mfma_kernel(
    u16* __restrict__ qkvbuf, const u16* __restrict__ qT, const u16* __restrict__ kT) {
  __shared__ __align__(16) u16 Kt[32 * 512];   // swizzled K tile, 32 KB
  __shared__ __align__(16) float ps[64][36];   // scores
  __shared__ __align__(16) u16 Pb[64][40];     // probs bf16
  __shared__ float alpha_s[64], invl_s[64];

  const int b = blockIdx.y;
  const int i0 = blockIdx.x * 64;
  const int t = threadIdx.x;
  const int w = t >> 6;
  const int lane = t & 63;
  const int quad = lane >> 4;
  const int m16 = lane & 15;
  const int mt_s = w & 3;   // S-phase m-tile (query group)
  const int nt_s = w >> 2;  // S-phase n-tile (key half)

  const u16* vb = qkvbuf + (size_t)b * BATCH_STRIDE + V_OFF;
  float* obuf = (float*)(qkvbuf + (size_t)b * BATCH_STRIDE + Q_OFF);  // aliases q+k
  const u16* qTb = qT + (size_t)b * (CC * NN);
  const u16* kTb = kT + (size_t)b * (CC * NN);

  // Q fragments in registers: A[m][k], m = lane&15, k = quad*8+j
  bf16x8 qf[16];
  {
    const u16* qrow = qTb + (size_t)(i0 + mt_s * 16 + m16) * CC + quad * 8;
#pragma unroll
    for (int kc = 0; kc < 16; ++kc) qf[kc] = *(const bf16x8*)(qrow + kc * 32);
  }

  float m_r = -1e30f, l_r = 0.f;  // row state for t<256: row=t>>2

  f32x4 oacc[4][4];
#pragma unroll
  for (int a = 0; a < 4; ++a)
#pragma unroll
    for (int c = 0; c < 4; ++c) oacc[a][c] = (f32x4){0.f, 0.f, 0.f, 0.f};

  // prefetch K tile 0: wave w stages rows j = it*8 + w; lane = physical unit
  uint4 kreg[4];
#pragma unroll
  for (int it = 0; it < 4; ++it) {
    const int j = it * 8 + w;
    const int u = lane ^ (j & 7);
    kreg[it] = *(const uint4*)(kTb + (size_t)j * CC + u * 8);
  }

  for (int j0 = 0; j0 < NN; j0 += 32) {
    __syncthreads();  // previous step's Kt consumers done
#pragma unroll
    for (int it = 0; it < 4; ++it) {
      const int j = it * 8 + w;
      *(uint4*)((char*)Kt + j * 1024 + lane * 16) = kreg[it];
    }
    if (j0 + 32 < NN) {
#pragma unroll
      for (int it = 0; it < 4; ++it) {
        const int j = it * 8 + w;
        const int u = lane ^ (j & 7);
        kreg[it] = *(const uint4*)(kTb + (size_t)(j0 + 32 + j) * CC + u * 8);
      }
    }
    // prefetch V fragments (B operand: n=c=lane&15, k=j=quad*8+jj, contiguous j)
    bf16x8 vf[4];
#pragma unroll
    for (int ct = 0; ct < 4; ++ct) {
      const int c = w * 64 + ct * 16 + m16;
      vf[ct] = *(const bf16x8*)(vb + (size_t)c * NN + j0 + quad * 8);
    }
    __syncthreads();  // Kt ready
    // ---- S = Q^T K for this wave's 16x16 tile ----
    f32x4 sacc = (f32x4){0.f, 0.f, 0.f, 0.f};
    {
      const int j = nt_s * 16 + m16;
      const char* krow = (const char*)Kt + j * 1024;
      const int swz = j & 7;
#pragma unroll
      for (int kc = 0; kc < 16; ++kc) {
        const int u = (kc * 4 + quad) ^ swz;
        bf16x8 kf = *(const bf16x8*)(krow + u * 16);
        sacc = __builtin_amdgcn_mfma_f32_16x16x32_bf16(qf[kc], kf, sacc, 0, 0, 0);
      }
    }
    {
      const int row = mt_s * 16 + quad * 4;
      const int col = nt_s * 16 + m16;
#pragma unroll
      for (int r = 0; r < 4; ++r) ps[row + r][col] = sacc[r] * SCALE;
    }
    __syncthreads();
    // ---- online softmax: t<256, row=t>>2, part=t&3 covers cols part*8..+8 ----
    if (t < 256) {
      const int row = t >> 2, part = t & 3;
      float4 s0 = *(const float4*)&ps[row][part * 8];
      float4 s1 = *(const float4*)&ps[row][part * 8 + 4];
      float mx = fmaxf(fmaxf(fmaxf(s0.x, s0.y), fmaxf(s0.z, s0.w)),
                       fmaxf(fmaxf(s1.x, s1.y), fmaxf(s1.z, s1.w)));
      mx = fmaxf(mx, __shfl_xor(mx, 1, 64));
      mx = fmaxf(mx, __shfl_xor(mx, 2, 64));
      const float mnew = fmaxf(m_r, mx);
      const float alpha = __expf(m_r - mnew);
      float p0 = __expf(s0.x - mnew), p1 = __expf(s0.y - mnew);
      float p2 = __expf(s0.z - mnew), p3 = __expf(s0.w - mnew);
      float p4 = __expf(s1.x - mnew), p5 = __expf(s1.y - mnew);
      float p6 = __expf(s1.z - mnew), p7 = __expf(s1.w - mnew);
      float sum = ((p0 + p1) + (p2 + p3)) + ((p4 + p5) + (p6 + p7));
      sum += __shfl_xor(sum, 1, 64);
      sum += __shfl_xor(sum, 2, 64);
      l_r = l_r * alpha + sum;
      m_r = mnew;
      if (part == 0) alpha_s[row] = alpha;
      uint4 pk;
      pk.x = (u32)f2bf(p0) | ((u32)f2bf(p1) << 16);
      pk.y = (u32)f2bf(p2) | ((u32)f2bf(p3) << 16);
      pk.z = (u32)f2bf(p4) | ((u32)f2bf(p5) << 16);
      pk.w = (u32)f2bf(p6) | ((u32)f2bf(p7) << 16);
      *(uint4*)&Pb[row][part * 8] = pk;
    }
    __syncthreads();
    // ---- PV: wave w owns channels [w*64, w*64+64) ----
    float4 alph[4];
#pragma unroll
    for (int mt = 0; mt < 4; ++mt)
      alph[mt] = *(const float4*)&alpha_s[mt * 16 + quad * 4];
#pragma unroll
    for (int mt = 0; mt < 4; ++mt) {
      bf16x8 pf = *(const bf16x8*)&Pb[mt * 16 + m16][quad * 8];
#pragma unroll
      for (int ct = 0; ct < 4; ++ct) {
        f32x4 o = oacc[mt][ct];
        o[0] *= alph[mt].x;
        o[1] *= alph[mt].y;
        o[2] *= alph[mt].z;
        o[3] *= alph[mt].w;
        oacc[mt][ct] = __builtin_amdgcn_mfma_f32_16x16x32_bf16(pf, vf[ct], o, 0, 0, 0);
      }
    }
  }
  if (t < 256 && (t & 3) == 0) invl_s[t >> 2] = 1.0f / l_r;
  __syncthreads();
#pragma unroll
  for (int mt = 0; mt < 4; ++mt) {
    float4 il = *(const float4*)&invl_s[mt * 16 + quad * 4];
#pragma unroll
    for (int ct = 0; ct < 4; ++ct) {
      const int c = w * 64 + ct * 16 + m16;
      float4 ov;
      ov.x = oacc[mt][ct][0] * il.x;
      ov.y = oacc[mt][ct][1] * il.y;
      ov.z = oacc[mt][ct][2] * il.z;
      ov.w = oacc[mt][ct][3] * il.w;
      *(float4*)(obuf + (size_t)c * NN + i0 + mt * 16 + quad * 4) = ov;
    }
  }
}

// ------------- output projection + bias + residual (obuf aliased in qkv ws) -------------
__global__ __launch_bounds__(256) void proj_kernel(
    const u16* __restrict__ qkvbuf, const float* __restrict__ wout,
    const float* __restrict__ bout, const float* __restrict__ x,
    float* __restrict__ out) {
  __shared__ __align__(16) float Wt[16][68];
  __shared__ __align__(16) float Ht[16][68];
  const int b = blockIdx.z;
  const int o0 = blockIdx.y * 64;
  const int n0 = blockIdx.x * 64;
  const int t = threadIdx.x;
  const int to = (t >> 4) * 4;
  const int tn = (t & 15) * 4;
  const int wo = t >> 2;
  const int wk = (t & 3) * 4;
  const int xc = t >> 4;
  const int xn = (t & 15) * 4;
  const float* ob = (const float*)(qkvbuf + (size_t)b * BATCH_STRIDE + Q_OFF);
  float acc[4][4] = {{0.f}};
  for (int kk = 0; kk < CC; kk += 16) {
    float4 wv = *(const float4*)(wout + (size_t)(o0 + wo) * CC + kk + wk);
    float4 hv = *(const float4*)(ob + (size_t)(kk + xc) * NN + n0 + xn);
    __syncthreads();
    Wt[wk + 0][wo] = wv.x;
    Wt[wk + 1][wo] = wv.y;
    Wt[wk + 2][wo] = wv.z;
    Wt[wk + 3][wo] = wv.w;
    *(float4*)&Ht[xc][xn] = hv;
    __syncthreads();
#pragma unroll
    for (int k = 0; k < 16; ++k) {
      float4 w4 = *(const float4*)&Wt[k][to];
      float4 h4 = *(const float4*)&Ht[k][tn];
      acc[0][0] = fmaf(w4.x, h4.x, acc[0][0]);
      acc[0][1] = fmaf(w4.x, h4.y, acc[0][1]);
      acc[0][2] = fmaf(w4.x, h4.z, acc[0][2]);
      acc[0][3] = fmaf(w4.x, h4.w, acc[0][3]);
      acc[1][0] = fmaf(w4.y, h4.x, acc[1][0]);
      acc[1][1] = fmaf(w4.y, h4.y, acc[1][1]);
      acc[1][2] = fmaf(w4.y, h4.z, acc[1][2]);
      acc[1][3] = fmaf(w4.y, h4.w, acc[1][3]);
      acc[2][0] = fmaf(w4.z, h4.x, acc[2][0]);
      acc[2][1] = fmaf(w4.z, h4.y, acc[2][1]);
      acc[2][2] = fmaf(w4.z, h4.z, acc[2][2]);
      acc[2][3] = fmaf(w4.z, h4.w, acc[2][3]);
      acc[3][0] = fmaf(w4.w, h4.x, acc[3][0]);
      acc[3][1] = fmaf(w4.w, h4.y, acc[3][1]);
      acc[3][2] = fmaf(w4.w, h4.z, acc[3][2]);
      acc[3][3] = fmaf(w4.w, h4.w, acc[3][3]);
    }
  }
#pragma unroll
  for (int i = 0; i < 4; ++i) {
    const int o = o0 + to + i;
    const float bias = bout[o];
    const size_t idx = ((size_t)b * CC + o) * NN + n0 + tn;
    float4 xv = *(const float4*)(x + idx);
    float4 r;
    r.x = acc[i][0] + bias + xv.x;
    r.y = acc[i][1] + bias + xv.y;
    r.z = acc[i][2] + bias + xv.z;
    r.w = acc[i][3] + bias + xv.w;
    *(float4*)(out + idx) = r;
  }
}

extern "C" void kernel_launch(void* const* d_in, const int* in_sizes, int n_in,
                              void* d_out, int out_size, void* d_ws, size_t ws_size,
                              hipStream_t stream) {
  const float* x = (const float*)d_in[0];
  const float* gamma = (const float*)d_in[1];
  const float* beta = (const float*)d_in[2];
  const float* wqkv = (const float*)d_in[3];
  const float* bqkv = (const float*)d_in[4];
  const float* wout = (const float*)d_in[5];
  const float* bout = (const float*)d_in[6];
  float* out = (float*)d_out;

  char* ws = (char*)d_ws;
  float* stats = (float*)ws;                           // 2 KB
  u16* qkv = (u16*)(ws + 4096);                        // 100.66 MB bf16 [v|q|k] per batch
  u16* qT = (u16*)(ws + 4096 + (size_t)BB * OQKV * NN * 2);      // 33.55 MB
  u16* kT = qT + (size_t)BB * CC * NN;                            // 33.55 MB

  gn_stats_kernel<<<BB * GG, 256, 0, stream>>>(x, stats);
  qkv_gemm_kernel<<<dim3(NN / 64, OQKV / 64, BB), 256, 0, stream>>>(
      x, gamma, beta, wqkv, bqkv, stats, qkv);
  transpose_qk_kernel<<<dim3(NN / 64, CC / 64, BB * 2), 256, 0, stream>>>(qkv, qT, kT);
  attn_mfma_kernel<<<dim3(NN / 64, BB), 512, 0, stream>>>(qkv, qT, kT);
  proj_kernel<<<dim3(NN / 64, CC / 64, BB), 256, 0, stream>>>(qkv, wout, bout, x, out);
}